// Round 13
// baseline (60.508 us; speedup 1.0000x reference)
//
#include <hip/hip_runtime.h>
#include <hip/hip_bf16.h>
#include <math.h>

namespace {

typedef __attribute__((ext_vector_type(8))) short bh8;   // 8 bf16 = 4 VGPR MFMA A/B frag
typedef __attribute__((ext_vector_type(4))) short sh4;   // 4 bf16 (8B)
typedef __attribute__((ext_vector_type(4))) float fx4;

constexpr int PPG  = 8 * 96 * 64;           // positions per g
constexpr float NLOG2E = -1.4426950408889634f;
constexpr float LOG2E2 =  2.8853900817779268f;
// ws layout (bytes)
constexpr size_t FWT_OFF = 0;                               // FwT bf16 [g][o][r][i]: 6.29 MB
constexpr size_t CA_OFF  = 6291456;                         // convA bf16 [g][co][64]: 64 KB
constexpr size_t GWT_OFF = CA_OFF + 65536;                  // GW table bf16 [g][24 slots][64][8]: 192 KB

__device__ inline ushort f2b(float f) {
  __hip_bfloat16 h = __float2bfloat16(f);
  return __builtin_bit_cast(ushort, h);
}
// sGat byte offset: [16 bc][16 rr][64 i] bf16 (2048 B/bc), XOR-swizzled
__device__ inline int swzG(int bc, int rr, int ib) {
  return (bc * 2048 + rr * 128 + ib) ^ (((rr + bc) & 7) << 4);
}
// sFeat ushort index: [24 rows][16 bc][8], slot rotated by row
__device__ inline int fswz(int l, int bc) {
  return (l * 16 + ((bc + l) & 15)) * 8;
}

#define MFMA16(a, b, c) __builtin_amdgcn_mfma_f32_16x16x32_bf16((a), (b), (c), 0, 0, 0)

// ================= prep_k: FwT transpose + gate-ext + convA + GW =================
__global__ __launch_bounds__(512)
void prep_k(const float* __restrict__ Fw, const float* __restrict__ Gh,
            const float* __restrict__ Gd, const float* __restrict__ bgd,
            const float* __restrict__ Gm, const float* __restrict__ bgm,
            const float* __restrict__ bgh,
            const float* __restrict__ Wd, const float* __restrict__ bd,
            const float* __restrict__ Wm, const float* __restrict__ bm,
            ushort* __restrict__ FwT, ushort* __restrict__ GWT,
            ushort* __restrict__ cA)
{
  __shared__ float tile[64 * 97];
  const int bid = blockIdx.x, t = threadIdx.x;
  if (bid < 512) {
    const int go = bid;
    const float* src = Fw + (size_t)go * 6144;
    ushort* dst = FwT + (size_t)go * 6144;
#pragma unroll
    for (int it = 0; it < 12; ++it) {
      const int idx = t + it * 512;
      tile[(idx / 96) * 97 + (idx % 96)] = src[idx];
    }
    __syncthreads();
#pragma unroll
    for (int it = 0; it < 12; ++it) {
      const int idx = t + it * 512;
      const int r = idx >> 6, i = idx & 63;
      dst[idx] = f2b(tile[i * 97 + r]);
    }
  } else if (bid < 576) {
    // gate-ext slots (f=2): GWT[g][sub*3+2][lane][8]; il>0 lanes -> 0
    const int e = (bid - 512) * 512 + t;      // 32768
    const int j = e & 7, lp = (e >> 3) & 63, sub = (e >> 9) & 7, g = e >> 12;
    const int il = lp >> 4, mr = lp & 15;
    const int o2 = (sub >> 2) * 64 + (sub & 3) * 16 + mr;
    float v = 0.f;
    if (il == 0) {
      if (j == 0)      v = Gd[g * 128 + o2];
      else if (j <= 4) v = Gm[(size_t)(g * 128 + o2) * 4 + (j - 1)];
      else if (j == 5) v = bgd[g * 128 + o2] + bgm[g * 128 + o2] + bgh[g * 128 + o2];
    }
    v *= (sub >= 4) ? LOG2E2 : NLOG2E;
    GWT[((size_t)(g * 24 + sub * 3 + 2) * 64 + lp) * 8 + j] = f2b(v);
  } else if (bid < 640) {
    // convA[g][co][k=tap*8+tch]
    const int e = (bid - 576) * 512 + t;      // 32768
    const int g = e >> 12, co = (e >> 6) & 63, k = e & 63;
    const int tap = k >> 3, tch = k & 7;
    float v = 0.f;
    if (tch == 0)      v = Wd[(g * 64 + co) * 8 + tap];
    else if (tch <= 4) v = Wm[((g * 64 + co) * 4 + (tch - 1)) * 8 + tap];
    else if (tch == 5 && tap == 0) v = bd[g * 64 + co] + bm[g * 64 + co];
    cA[e] = f2b(v);
  } else {
    // GW = scale * (Gh . Wc), slot layout
    const int e = (bid - 640) * 512 + t;      // 65536
    const int row = e >> 6, k = e & 63;
    const int g = row >> 7, o2 = row & 127;
    const int tap = k >> 3, tch = k & 7;
    const float* pA; int sA = 0; float mA = 0.f, mB = 0.f;
    const float* pB;
    if (tch == 0)      { pA = Wd + (size_t)(g * 64) * 8 + tap; sA = 8;  mA = 1.f; }
    else if (tch <= 4) { pA = Wm + ((size_t)(g * 64) * 4 + (tch - 1)) * 8 + tap; sA = 32; mA = 1.f; }
    else if (tch == 5 && tap == 0) { pA = bd + g * 64; sA = 1; mA = 1.f; mB = 1.f; }
    else               { pA = Wd; }
    pB = (mB != 0.f) ? (bm + g * 64) : pA;
    const float* gh = Gh + (size_t)(g * 128 + o2) * 64;
    float acc = 0.f;
#pragma unroll 8
    for (int i = 0; i < 64; ++i) {
      const float wv = fmaf(mB, pB[i], mA * pA[i * sA]);
      acc = fmaf(gh[i], wv, acc);
    }
    acc *= (o2 >= 64) ? LOG2E2 : NLOG2E;
    const int half = o2 >> 6, s = (o2 >> 4) & 3, mr = o2 & 15;
    const int sub = half * 4 + s, fs = k >> 5, lp = ((k & 31) >> 3) * 16 + mr, j = k & 7;
    GWT[((size_t)(g * 24 + sub * 3 + fs) * 64 + lp) * 8 + j] = f2b(acc);
  }
}

// ================= main: 16-wave whole-output blocks, in-kernel pack, direct out =================
__global__ __launch_bounds__(1024, 1)
void fused_v12(const float* __restrict__ x, const float* __restrict__ xm,
               const ushort* __restrict__ FwT, const ushort* __restrict__ cA,
               const ushort* __restrict__ GWT, const float* __restrict__ bf,
               float* __restrict__ out)
{
  __shared__ __align__(16) ushort sTab[16384];     // 32 KB: slots 0-7 aC, 8-31 GW
  __shared__ __align__(16) char  sGat[2][32768];   // 64 KB gated hid dbuf [16bc][16rr][64i]
  __shared__ __align__(16) ushort sFeat[2][3072];  // 12 KB feat window dbuf [24 r][16 bc][8]
  __shared__ float sRed[4096];                     // 16 KB fc i-quarter reduce

  const int t    = threadIdx.x;
  const int lane = t & 63;
  const int w    = t >> 6;          // 0..15
  const int il   = lane >> 4;
  const int mr   = lane & 15;
  const int bid  = blockIdx.x;
  const int g    = bid & 7;         // XCD-affine (256 % 8 == 0, bijective)
  const int bcT  = bid >> 3;        // 0..31
  const int s4   = w & 3, hq = w >> 2;   // fc role: o-subtile, i-quarter
  const int tb   = lane * 8;

  // ---- staging geometry (threads 0..383): l = t>>4 (0..23), bc = t&15 ----
  const int sl = t >> 4, sbc = t & 15;
  const int sbcg = bcT * 16 + sbc;
  const size_t sposb = ((size_t)(sbcg >> 6) * 96) * 64 + (sbcg & 63);
  const int sadr = fswz(sl, sbc);

  // ---- stage tables: aC (waves 0-7 -> slots 0-7), GW (24 KB linear) ----
  if (w < 8)
    *(bh8*)&sTab[w * 512 + tb] =
        *(const bh8*)(cA + g * 4096 + ((w >> 1) * 16 + mr) * 64 + (w & 1) * 32 + il * 8);
  {
    const ushort* gsrc = GWT + (size_t)g * 12288;
#pragma unroll
    for (int it = 0; it < 2; ++it) {
      const int idx = it * 1024 + t;
      if (idx < 1536)
        *(bh8*)&sTab[4096 + idx * 8] = *(const bh8*)(gsrc + idx * 8);
    }
  }
  // ---- prologue: stage chunk-0 window rows q = l-8 (zpad q<0 keeps bias lane) ----
  if (t < 384) {
    const int q = sl - 8;
    bh8 o;
    if (q >= 0) {
      const size_t pi = (sposb + (size_t)q * 64) * 8 + g;
      const float xs = x[pi];
      const fx4 m = *(const fx4*)(xm + pi * 4);
      o[0] = (short)f2b(xs);
      o[1] = (short)f2b(m[0]); o[2] = (short)f2b(m[1]);
      o[3] = (short)f2b(m[2]); o[4] = (short)f2b(m[3]);
      o[5] = (short)0x3F80; o[6] = 0; o[7] = 0;
    } else {
      bh8 z = {0, 0, 0, 0, 0, (short)0x3F80, 0, 0};
      o = z;
    }
    *(bh8*)&sFeat[0][sadr] = o;
  }

  // ---- fixed per-thread addresses ----
  const int a_b0 = fswz(mr + il, w);        // conv taps 0-3 row
  const int a_b1 = fswz(mr + il + 4, w);    // conv taps 4-7 row
  const int a_bx = fswz(mr + 8, w);         // gate-ext row (r0+rr)
  int wadr[4];
#pragma unroll
  for (int s = 0; s < 4; ++s) wadr[s] = swzG(w, mr, s * 32 + il * 8);
  const ushort* fb0 = FwT + ((size_t)(g * 64 + s4 * 16 + mr) * 96) * 64 + hq * 16 + (il & 1) * 8;
  const int rsub = il >> 1;                 // rr within pair

  fx4 facc = {0.f, 0.f, 0.f, 0.f};
  __syncthreads();   // B0: tables + sFeat[0]

  int cur = 0;
#pragma unroll 1
  for (int k6 = 0; k6 < 6; ++k6) {
    const int r0 = k6 * 16;

    // ---- issue-early: next window stage loads + this chunk's aF loads ----
    bh8 stg;
    const bool do_stage = (t < 384) && (k6 < 5);
    if (do_stage) {
      const size_t pi = (sposb + (size_t)(r0 + 8 + sl) * 64) * 8 + g;
      const float xs = x[pi];
      const fx4 m = *(const fx4*)(xm + pi * 4);
      stg[0] = (short)f2b(xs);
      stg[1] = (short)f2b(m[0]); stg[2] = (short)f2b(m[1]);
      stg[3] = (short)f2b(m[2]); stg[4] = (short)f2b(m[3]);
      stg[5] = (short)0x3F80; stg[6] = 0; stg[7] = 0;
    }
    bh8 aF[8];
#pragma unroll
    for (int f = 0; f < 8; ++f)
      aF[f] = *(const bh8*)(fb0 + (size_t)(r0 + f * 2 + rsub) * 64);

    // ---- B-frags (wave's own bc = w, rr = mr) ----
    const bh8 b0 = *(const bh8*)&sFeat[cur][a_b0];
    const bh8 b1 = *(const bh8*)&sFeat[cur][a_b1];
    const bh8 bx = *(const bh8*)&sFeat[cur][a_bx];

    // ---------- conv: ah = hid0 ----------
    fx4 ah[4];
#pragma unroll
    for (int s = 0; s < 4; ++s) {
      const bh8 a0 = *(const bh8*)&sTab[(s * 2 + 0) * 512 + tb];
      const bh8 a1 = *(const bh8*)&sTab[(s * 2 + 1) * 512 + tb];
      fx4 a = {0.f, 0.f, 0.f, 0.f};
      a = MFMA16(a0, b0, a);
      a = MFMA16(a1, b1, a);
      ah[s] = a;
    }

    // ---------- gate: GW . F + epilogue ----------
    char* gbuf = sGat[cur];
#pragma unroll
    for (int s = 0; s < 4; ++s) {
      const int bs = (8 + s * 3) * 512 + tb;
      const int bt = (8 + (4 + s) * 3) * 512 + tb;
      fx4 aS = {0.f,0.f,0.f,0.f}, aT = {0.f,0.f,0.f,0.f};
      aS = MFMA16(*(const bh8*)&sTab[bs],        b0, aS);
      aS = MFMA16(*(const bh8*)&sTab[bs + 512],  b1, aS);
      aS = MFMA16(*(const bh8*)&sTab[bs + 1024], bx, aS);
      aT = MFMA16(*(const bh8*)&sTab[bt],        b0, aT);
      aT = MFMA16(*(const bh8*)&sTab[bt + 512],  b1, aT);
      aT = MFMA16(*(const bh8*)&sTab[bt + 1024], bx, aT);
      sh4 o4;
#pragma unroll
      for (int cc = 0; cc < 4; ++cc) {
        const float sig = __builtin_amdgcn_rcpf(1.f + exp2f(aS[cc]));    // 1/(1+e^{-g1})
        const float y   = exp2f(aT[cc]);                                 // e^{2 g2}
        const float th  = fmaf(-2.f, __builtin_amdgcn_rcpf(y + 1.f), 1.f); // tanh(g2)
        o4[cc] = (short)f2b(fmaf(sig, ah[s][cc] - th, th));
      }
      *(sh4*)(gbuf + wadr[s]) = o4;
    }

    // ---- write-late: commit next window ----
    if (do_stage) *(bh8*)&sFeat[cur ^ 1][sadr] = stg;
    __syncthreads();   // B(k): gbuf + sFeat[next] ready

    // ---------- fc: k = (rr-pair, i-quarter hq), aF in regs ----------
#pragma unroll
    for (int f = 0; f < 8; ++f) {
      const bh8 bF = *(const bh8*)(gbuf + swzG(mr, f * 2 + rsub, hq * 32 + (il & 1) * 16));
      facc = MFMA16(aF[f], bF, facc);
    }
    cur ^= 1;
  }

  // ---- i-quarter reduce + coalesced out write ----
#pragma unroll
  for (int cc = 0; cc < 4; ++cc)
    sRed[(hq * 4 + s4) * 256 + (4 * il + cc) * 16 + mr] = facc[cc];
  __syncthreads();
  {
    const int o = t & 63, bc = t >> 6;
    const int os4 = o >> 4, ol = o & 15;
    float s = bf[g * 64 + o];
#pragma unroll
    for (int hh = 0; hh < 4; ++hh)
      s += sRed[(hh * 4 + os4) * 256 + ol * 16 + bc];
    out[((size_t)(bcT * 16 + bc) * 8 + g) * 64 + o] = s;
  }
}

} // namespace

extern "C" void kernel_launch(void* const* d_in, const int* in_sizes, int n_in,
                              void* d_out, int out_size, void* d_ws, size_t ws_size,
                              hipStream_t stream) {
  const float* x   = (const float*)d_in[0];
  const float* xm  = (const float*)d_in[1];
  const float* Wd  = (const float*)d_in[2];
  const float* bd  = (const float*)d_in[3];
  const float* Wm  = (const float*)d_in[4];
  const float* bm  = (const float*)d_in[5];
  const float* Gd  = (const float*)d_in[6];
  const float* bgd = (const float*)d_in[7];
  const float* Gm  = (const float*)d_in[8];
  const float* bgm = (const float*)d_in[9];
  const float* Gh  = (const float*)d_in[10];
  const float* bgh = (const float*)d_in[11];
  const float* Fw  = (const float*)d_in[12];
  const float* bf  = (const float*)d_in[13];
  float* outp = (float*)d_out;

  ushort* FwT = (ushort*)((char*)d_ws + FWT_OFF);
  ushort* cA  = (ushort*)((char*)d_ws + CA_OFF);
  ushort* GWT = (ushort*)((char*)d_ws + GWT_OFF);

  prep_k<<<dim3(768), dim3(512), 0, stream>>>(
      Fw, Gh, Gd, bgd, Gm, bgm, bgh, Wd, bd, Wm, bm, FwT, GWT, cA);
  fused_v12<<<dim3(256), dim3(1024), 0, stream>>>(x, xm, FwT, cA, GWT, bf, outp);
}

// Round 15
// 51.619 us; speedup vs baseline: 1.1722x; 1.1722x over previous
//
#include <hip/hip_runtime.h>
#include <hip/hip_bf16.h>
#include <math.h>

namespace {

typedef __attribute__((ext_vector_type(8))) short bh8;   // 8 bf16 = 4 VGPR MFMA A/B frag
typedef __attribute__((ext_vector_type(4))) short sh4;   // 4 bf16 (8B)
typedef __attribute__((ext_vector_type(4))) float fx4;

constexpr int Rn = 96, Cn = 64, CINn = 8, COUTn = 64;
constexpr int NPOS = 8 * 96 * 64 * 8;       // 393216 (b,r,c,g) positions
constexpr int PPG  = 8 * 96 * 64;           // 49152 (b,r,c) per g
constexpr float NLOG2E = -1.4426950408889634f;
constexpr float LOG2E2 =  2.8853900817779268f;
// ws layout (bytes)
constexpr size_t FEAT_OFF = 0;                                // feat bf16x8, G-MAJOR [g][pb]: 6.29 MB
constexpr size_t FWT_OFF  = (size_t)NPOS * 16;                // FwT bf16 [g][o][r][i]: 6.29 MB
constexpr size_t CA_OFF   = FWT_OFF + (size_t)NPOS * 16;      // convA bf16 [g][co][64]: 64 KB
constexpr size_t GWT_OFF  = CA_OFF + 65536;                   // GW table bf16 [g][24 slots][64][8]: 192 KB
constexpr size_t PART_OFF = GWT_OFF + 196608;                 // partials f32 [16][32][1024]: 2 MB

__device__ inline ushort f2b(float f) {
  __hip_bfloat16 h = __float2bfloat16(f);
  return __builtin_bit_cast(ushort, h);
}
// hardware packed f32x2 -> bf16x2 (RNE) — verified T12 recipe
__device__ inline unsigned cvtpk(float lo, float hi) {
  unsigned r;
  asm("v_cvt_pk_bf16_f32 %0, %1, %2" : "=v"(r) : "v"(lo), "v"(hi));
  return r;
}
// swizzled byte offset into a [16 bc][8 rr][64 i] bf16 buffer (128B rows, 16KB)
__device__ inline int swz8(int bc, int rr, int ib) {
  return (bc * 1024 + rr * 128 + ib) ^ (((rr + bc) & 7) << 4);
}
// sFeat ushort index: [16 rows][16 bc][8], bc XOR-swizzled by row
__device__ inline int fswz(int l, int bc) {
  return (l * 16 + (bc ^ (l & 7))) * 8;
}

#define MFMA16(a, b, c) __builtin_amdgcn_mfma_f32_16x16x32_bf16((a), (b), (c), 0, 0, 0)

// ================= prep_k: feat pack + FwT transpose + gate-ext + convA + GW =================
__global__ __launch_bounds__(512)
void prep_k(const float* __restrict__ x, const float* __restrict__ xm,
            const float* __restrict__ Fw, const float* __restrict__ Gh,
            const float* __restrict__ Gd, const float* __restrict__ bgd,
            const float* __restrict__ Gm, const float* __restrict__ bgm,
            const float* __restrict__ bgh,
            const float* __restrict__ Wd, const float* __restrict__ bd,
            const float* __restrict__ Wm, const float* __restrict__ bm,
            ushort* __restrict__ feat, ushort* __restrict__ FwT,
            ushort* __restrict__ GWT, ushort* __restrict__ cA)
{
  __shared__ float tile[64 * 97];
  const int bid = blockIdx.x, t = threadIdx.x;
  if (bid < 768) {
    const int pos = bid * 512 + t;
    const float xs = x[pos];
    const fx4 m = *(const fx4*)(xm + (size_t)pos * 4);
    bh8 o;
    o[0] = (short)f2b(xs);
    o[1] = (short)f2b(m[0]); o[2] = (short)f2b(m[1]);
    o[3] = (short)f2b(m[2]); o[4] = (short)f2b(m[3]);
    o[5] = (short)0x3F80; o[6] = 0; o[7] = 0;
    const int g = pos & 7, pb = pos >> 3;
    *(bh8*)(feat + ((size_t)g * PPG + pb) * 8) = o;
  } else if (bid < 1280) {
    const int go = bid - 768;
    const float* src = Fw + (size_t)go * 6144;
    ushort* dst = FwT + (size_t)go * 6144;
#pragma unroll
    for (int it = 0; it < 12; ++it) {
      const int idx = t + it * 512;
      tile[(idx / 96) * 97 + (idx % 96)] = src[idx];
    }
    __syncthreads();
#pragma unroll
    for (int it = 0; it < 12; ++it) {
      const int idx = t + it * 512;
      const int r = idx >> 6, i = idx & 63;
      dst[idx] = f2b(tile[i * 97 + r]);
    }
  } else if (bid < 1344) {
    // gate-ext slots (f=2): GWT[g][sub*3+2][lane][8]; il>0 lanes -> 0
    const int e = (bid - 1280) * 512 + t;     // 32768
    const int j = e & 7, lp = (e >> 3) & 63, sub = (e >> 9) & 7, g = e >> 12;
    const int il = lp >> 4, mr = lp & 15;
    const int o2 = (sub >> 2) * 64 + (sub & 3) * 16 + mr;
    float v = 0.f;
    if (il == 0) {
      if (j == 0)      v = Gd[g * 128 + o2];
      else if (j <= 4) v = Gm[(size_t)(g * 128 + o2) * 4 + (j - 1)];
      else if (j == 5) v = bgd[g * 128 + o2] + bgm[g * 128 + o2] + bgh[g * 128 + o2];
    }
    v *= (sub >= 4) ? LOG2E2 : NLOG2E;
    GWT[((size_t)(g * 24 + sub * 3 + 2) * 64 + lp) * 8 + j] = f2b(v);
  } else if (bid < 1408) {
    // convA[g][co][k=tap*8+tch]
    const int e = (bid - 1344) * 512 + t;     // 32768
    const int g = e >> 12, co = (e >> 6) & 63, k = e & 63;
    const int tap = k >> 3, tch = k & 7;
    float v = 0.f;
    if (tch == 0)      v = Wd[(g * 64 + co) * 8 + tap];
    else if (tch <= 4) v = Wm[((g * 64 + co) * 4 + (tch - 1)) * 8 + tap];
    else if (tch == 5 && tap == 0) v = bd[g * 64 + co] + bm[g * 64 + co];
    cA[e] = f2b(v);
  } else {
    // GW = scale * (Gh . Wc), slot layout
    const int e = (bid - 1408) * 512 + t;     // 65536
    const int row = e >> 6, k = e & 63;
    const int g = row >> 7, o2 = row & 127;
    const int tap = k >> 3, tch = k & 7;
    const float* pA; int sA = 0; float mA = 0.f, mB = 0.f;
    const float* pB;
    if (tch == 0)      { pA = Wd + (size_t)(g * 64) * 8 + tap; sA = 8;  mA = 1.f; }
    else if (tch <= 4) { pA = Wm + ((size_t)(g * 64) * 4 + (tch - 1)) * 8 + tap; sA = 32; mA = 1.f; }
    else if (tch == 5 && tap == 0) { pA = bd + g * 64; sA = 1; mA = 1.f; mB = 1.f; }
    else               { pA = Wd; }
    pB = (mB != 0.f) ? (bm + g * 64) : pA;
    const float* gh = Gh + (size_t)(g * 128 + o2) * 64;
    float acc = 0.f;
#pragma unroll 8
    for (int i = 0; i < 64; ++i) {
      const float wv = fmaf(mB, pB[i], mA * pA[i * sA]);
      acc = fmaf(gh[i], wv, acc);
    }
    acc *= (o2 >= 64) ? LOG2E2 : NLOG2E;
    const int half = o2 >> 6, s = (o2 >> 4) & 3, mr = o2 & 15;
    const int sub = half * 4 + s, fs = k >> 5, lp = ((k & 31) >> 3) * 16 + mr, j = k & 7;
    GWT[((size_t)(g * 24 + sub * 3 + fs) * 64 + lp) * 8 + j] = f2b(acc);
  }
}

// ================= main: LDS-staged feat, aF prefetch, HW exp2/cvt_pk epilogue =================
__global__ __launch_bounds__(512, 2)
void fused_v14(const ushort* __restrict__ feat, const ushort* __restrict__ FwT,
               const ushort* __restrict__ cA, const ushort* __restrict__ GWT,
               float* __restrict__ part)
{
  __shared__ __align__(16) ushort sTab[16384];     // 32 KB: slots 0-7 aC, 8-31 GW
  __shared__ __align__(16) char sGat[2][16384];    // gated hid, double-buffered
  __shared__ __align__(16) ushort sFeat[2][2048];  // 2x4 KB feat tile [16 rows][16 bc][8]
  __shared__ float sRed[1024];                     // fc hf-reduce

  const int t    = threadIdx.x;
  const int lane = t & 63;
  const int w    = t >> 6;
  const int il   = lane >> 4;
  const int mr   = lane & 15;
  const int bid  = blockIdx.x;
  const int g    = bid & 7;                    // XCD-affine (512 % 8 == 0, bijective)
  const int bcT  = (bid >> 3) & 31;
  const int chh  = bid >> 8;                   // 0..1 -> rows chh*48 .. chh*48+47
  const ushort* fg = feat + (size_t)g * PPG * 8;
  const int s4   = w & 3, hf = w >> 2;
  const int tb   = lane * 8;

  // ---- this wave's 16 positions: pglob = w*16+mr ----
  const int pglob = w * 16 + mr;
  const int cbcl = pglob >> 3, crr = pglob & 7;

  // ---- staging geometry (threads 0..255): row l = t>>4, bc = t&15 ----
  const int sl = t >> 4, sbc = t & 15;
  const int sbcg = bcT * 16 + sbc;
  const size_t sprow = (size_t)((sbcg >> 6) * 96) * 64 + (sbcg & 63);
  const int sadr = fswz(sl, sbc);
  const bh8 zpad = {0, 0, 0, 0, 0, (short)0x3F80, 0, 0};

  // ---- stage tables: aC (wave w -> slot w), GW (linear 24KB copy) ----
  *(bh8*)&sTab[w * 512 + tb] =
      *(const bh8*)(cA + g * 4096 + ((w >> 1) * 16 + mr) * 64 + (w & 1) * 32 + il * 8);
  {
    const ushort* gsrc = GWT + (size_t)g * 12288;
#pragma unroll
    for (int it = 0; it < 3; ++it) {
      const int idx = it * 512 + t;
      *(bh8*)&sTab[4096 + idx * 8] = *(const bh8*)(gsrc + idx * 8);
    }
  }
  // ---- prologue: stage chunk-0 feat rows (q = chh*48 - 8 + l), zpad for q<0 ----
  if (t < 256) {
    const int q = chh * 48 - 8 + sl;
    *(bh8*)&sFeat[0][sadr] =
        (q >= 0) ? *(const bh8*)(fg + (sprow + (size_t)q * 64) * 8) : zpad;
  }

  // ---- B-frag LDS addresses (ushort idx, fixed per thread) ----
  const int a_b0 = fswz(crr + il, cbcl);
  const int a_b1 = fswz(crr + il + 4, cbcl);
  const int a_bx = fswz(crr + 8, cbcl);
  int wadr[4];
#pragma unroll
  for (int s = 0; s < 4; ++s) wadr[s] = swz8(cbcl, crr, s * 32 + il * 8);
  const ushort* fb0 = FwT + ((size_t)(g * 64 + s4 * 16 + mr) * 96) * 64 + 32 * hf + 8 * il;

  fx4 facc = {0.f, 0.f, 0.f, 0.f};
  __syncthreads();   // B0: tables + sFeat[0] staged

  int cur = 0;
#pragma unroll 1
  for (int k6 = 0; k6 < 6; ++k6) {
    const int r0 = chh * 48 + k6 * 8;

    // ---- issue-early: next chunk's feat stage loads + this chunk's aF loads ----
    bh8 stg;
    const bool do_stage = (t < 256) && (k6 < 5);
    if (do_stage)
      stg = *(const bh8*)(fg + (sprow + (size_t)(r0 + sl) * 64) * 8);
    bh8 aF[8];
    {
      const ushort* fb = fb0 + (size_t)r0 * 64;
#pragma unroll
      for (int f = 0; f < 8; ++f) aF[f] = *(const bh8*)(fb + f * 64);
    }

    // ---- B-frags from sFeat[cur] ----
    const bh8 b0 = *(const bh8*)&sFeat[cur][a_b0];
    const bh8 b1 = *(const bh8*)&sFeat[cur][a_b1];
    const bh8 bx = *(const bh8*)&sFeat[cur][a_bx];

    // ---------- conv: ah = hid0 for own positions ----------
    fx4 ah[4];
#pragma unroll
    for (int s = 0; s < 4; ++s) {
      const bh8 a0 = *(const bh8*)&sTab[(s * 2 + 0) * 512 + tb];
      const bh8 a1 = *(const bh8*)&sTab[(s * 2 + 1) * 512 + tb];
      fx4 a = {0.f, 0.f, 0.f, 0.f};
      a = MFMA16(a0, b0, a);
      a = MFMA16(a1, b1, a);
      ah[s] = a;
    }

    // ---------- gate: GW . F + HW exp2/rcp/cvt_pk epilogue ----------
    char* gbuf = sGat[k6 & 1];
#pragma unroll
    for (int s = 0; s < 4; ++s) {
      const int bs = (8 + s * 3) * 512 + tb;
      const int bt = (8 + (4 + s) * 3) * 512 + tb;
      fx4 aS = {0.f,0.f,0.f,0.f}, aT = {0.f,0.f,0.f,0.f};
      aS = MFMA16(*(const bh8*)&sTab[bs],        b0, aS);
      aS = MFMA16(*(const bh8*)&sTab[bs + 512],  b1, aS);
      aS = MFMA16(*(const bh8*)&sTab[bs + 1024], bx, aS);
      aT = MFMA16(*(const bh8*)&sTab[bt],        b0, aT);
      aT = MFMA16(*(const bh8*)&sTab[bt + 512],  b1, aT);
      aT = MFMA16(*(const bh8*)&sTab[bt + 1024], bx, aT);
      float hv[4];
#pragma unroll
      for (int cc = 0; cc < 4; ++cc) {
        const float sig = __builtin_amdgcn_rcpf(1.f + __builtin_amdgcn_exp2f(aS[cc]));
        const float th  = fmaf(-2.f, __builtin_amdgcn_rcpf(1.f + __builtin_amdgcn_exp2f(aT[cc])), 1.f);
        hv[cc] = fmaf(sig, ah[s][cc] - th, th);
      }
      uint2 pk;
      pk.x = cvtpk(hv[0], hv[1]);
      pk.y = cvtpk(hv[2], hv[3]);
      *(uint2*)(gbuf + wadr[s]) = pk;
    }

    // ---- write-late: commit next chunk's feat tile ----
    if (do_stage) *(bh8*)&sFeat[cur ^ 1][sadr] = stg;
    __syncthreads();   // B(k): gbuf + sFeat[nxt] ready

    // ---------- fc: aF already in regs ----------
#pragma unroll
    for (int f = 0; f < 8; ++f) {
      const bh8 bF = *(const bh8*)(gbuf + swz8(mr, f, 64 * hf + 16 * il));
      facc = MFMA16(aF[f], bF, facc);
    }
    cur ^= 1;
  }

  // ---- hf-reduce + write partial ----
  if (hf == 1) {
#pragma unroll
    for (int cc = 0; cc < 4; ++cc)
      sRed[s4 * 256 + (4 * il + cc) * 16 + mr] = facc[cc];
  }
  __syncthreads();
  if (hf == 0) {
    float* pp = part + ((size_t)(chh * 8 + g) * 32 + bcT) * 1024;
#pragma unroll
    for (int cc = 0; cc < 4; ++cc)
      pp[mr * 64 + s4 * 16 + 4 * il + cc] = facc[cc] + sRed[s4 * 256 + (4 * il + cc) * 16 + mr];
  }
}

// ================= reduce: out = part(chh=0) + part(chh=1) + bias =================
__global__ __launch_bounds__(256)
void reduce_k(const float* __restrict__ part, const float* __restrict__ bf,
              float* __restrict__ out)
{
  const int e = blockIdx.x * 256 + threadIdx.x;     // 262144 outputs
  const int o = e & 63, g = (e >> 6) & 7, bcg = e >> 9;
  const int bcT = bcg >> 4, bcl = bcg & 15;
  const float s = bf[g * 64 + o]
      + part[((size_t)(0 * 8 + g) * 32 + bcT) * 1024 + bcl * 64 + o]
      + part[((size_t)(1 * 8 + g) * 32 + bcT) * 1024 + bcl * 64 + o];
  out[e] = s;
}

} // namespace

extern "C" void kernel_launch(void* const* d_in, const int* in_sizes, int n_in,
                              void* d_out, int out_size, void* d_ws, size_t ws_size,
                              hipStream_t stream) {
  const float* x   = (const float*)d_in[0];
  const float* xm  = (const float*)d_in[1];
  const float* Wd  = (const float*)d_in[2];
  const float* bd  = (const float*)d_in[3];
  const float* Wm  = (const float*)d_in[4];
  const float* bm  = (const float*)d_in[5];
  const float* Gd  = (const float*)d_in[6];
  const float* bgd = (const float*)d_in[7];
  const float* Gm  = (const float*)d_in[8];
  const float* bgm = (const float*)d_in[9];
  const float* Gh  = (const float*)d_in[10];
  const float* bgh = (const float*)d_in[11];
  const float* Fw  = (const float*)d_in[12];
  const float* bf  = (const float*)d_in[13];
  float* outp = (float*)d_out;

  ushort* feat = (ushort*)((char*)d_ws + FEAT_OFF);
  ushort* FwT  = (ushort*)((char*)d_ws + FWT_OFF);
  ushort* cA   = (ushort*)((char*)d_ws + CA_OFF);
  ushort* GWT  = (ushort*)((char*)d_ws + GWT_OFF);
  float*  part = (float*)((char*)d_ws + PART_OFF);

  prep_k<<<dim3(1536), dim3(512), 0, stream>>>(
      x, xm, Fw, Gh, Gd, bgd, Gm, bgm, bgh, Wd, bd, Wm, bm, feat, FwT, GWT, cA);
  fused_v14<<<dim3(512), dim3(512), 0, stream>>>(feat, FwT, cA, GWT, part);
  reduce_k<<<dim3(1024), dim3(256), 0, stream>>>(part, bf, outp);
}